// Round 5
// baseline (554.270 us; speedup 1.0000x reference)
//
#include <hip/hip_runtime.h>
#include <hip/hip_bf16.h>

// Problem constants: B=4, S=1024, D=1024, H=16, HD=64
#define SS 1024
#define DD 1024
#define HH 16
#define HDh 64

typedef short bf16x8 __attribute__((ext_vector_type(8)));
typedef float f32x4 __attribute__((ext_vector_type(4)));

__device__ inline unsigned short f2bf(float f) {
    union { __hip_bfloat16 h; unsigned short u; } cv;
    cv.h = __float2bfloat16(f);   // RTNE
    return cv.u;
}

// Pin a fragment into VGPRs at this program point: the compiler cannot sink the
// producing load below this, and must keep the value live. (CK idiom.)
#define PIN4(a, b, c, d) asm volatile("" : "+v"(a), "+v"(b), "+v"(c), "+v"(d))

// async global->LDS, 16B per lane; LDS dest = wave-uniform base + lane*16
__device__ inline void gload_lds16(const unsigned short* g, unsigned short* l) {
    __builtin_amdgcn_global_load_lds(
        (const __attribute__((address_space(1))) unsigned int*)g,
        (__attribute__((address_space(3))) unsigned int*)l, 16, 0, 0);
}

// ---------------- fp32 -> bf16 convert for query/key/value ----------------
__global__ __launch_bounds__(256) void cvt3(
    const float* __restrict__ a, const float* __restrict__ b, const float* __restrict__ c,
    unsigned short* __restrict__ oa, unsigned short* __restrict__ ob, unsigned short* __restrict__ oc)
{
    size_t i = ((size_t)blockIdx.x * 256 + threadIdx.x) * 4;
    float4 va = *(const float4*)(a + i);
    float4 vb = *(const float4*)(b + i);
    float4 vc = *(const float4*)(c + i);
    *(ushort4*)(oa + i) = make_ushort4(f2bf(va.x), f2bf(va.y), f2bf(va.z), f2bf(va.w));
    *(ushort4*)(ob + i) = make_ushort4(f2bf(vb.x), f2bf(vb.y), f2bf(vb.z), f2bf(vb.w));
    *(ushort4*)(oc + i) = make_ushort4(f2bf(vc.x), f2bf(vc.y), f2bf(vc.z), f2bf(vc.w));
}

// ------------- weight transpose-convert: Wt[e][d] = bf16(W[d][e]) -------------
__global__ __launch_bounds__(256) void wtrans(
    const float* __restrict__ Wq, const float* __restrict__ Wk,
    const float* __restrict__ Wv, const float* __restrict__ Wo,
    unsigned short* __restrict__ oq, unsigned short* __restrict__ ok,
    unsigned short* __restrict__ ov, unsigned short* __restrict__ oo)
{
    __shared__ float tile[32][33];
    int z = blockIdx.z;
    const float* W = z == 0 ? Wq : (z == 1 ? Wk : (z == 2 ? Wv : Wo));
    unsigned short* O = z == 0 ? oq : (z == 1 ? ok : (z == 2 ? ov : oo));
    int e0 = blockIdx.x * 32, d0 = blockIdx.y * 32;
    int r = threadIdx.x >> 3, c4 = (threadIdx.x & 7) * 4;
    float4 v = *(const float4*)(W + (size_t)(d0 + r) * DD + e0 + c4);
    tile[r][c4 + 0] = v.x; tile[r][c4 + 1] = v.y; tile[r][c4 + 2] = v.z; tile[r][c4 + 3] = v.w;
    __syncthreads();
    ushort4 u = make_ushort4(f2bf(tile[c4 + 0][r]), f2bf(tile[c4 + 1][r]),
                             f2bf(tile[c4 + 2][r]), f2bf(tile[c4 + 3][r]));
    *(ushort4*)(O + (size_t)(e0 + r) * DD + d0 + c4) = u;
}

// ---------------- 128x128 bf16 MFMA GEMM core, m97-style staging ----------------
__device__ inline void gemm128_core(const unsigned short* __restrict__ A,
                                    const unsigned short* __restrict__ Bt,
                                    const float* __restrict__ bias,
                                    void* __restrict__ out, int mode, float oscale)
{
    __shared__ unsigned short As[128 * 32];   // 8 KB
    __shared__ unsigned short Bs[128 * 32];   // 8 KB
    int t = threadIdx.x;
    int m0 = blockIdx.y * 128, n0 = blockIdx.x * 128;
    int w = t >> 6, lane = t & 63, quad = lane >> 4, l15 = lane & 15;
    int wm = w >> 1, wn = w & 1;

    f32x4 zero = {0.f, 0.f, 0.f, 0.f};
    f32x4 acc[4][4];
#pragma unroll
    for (int i = 0; i < 4; i++)
#pragma unroll
        for (int j = 0; j < 4; j++) acc[i][j] = zero;

    for (int k0 = 0; k0 < DD; k0 += 32) {
        __syncthreads();
#pragma unroll
        for (int i = 0; i < 4; i++) {
            int chunk = w + i * 4;            // 0..15
            int half = chunk >> 3;            // 0=A, 1=B
            int c = chunk & 7;                // 16-row chunk within matrix
            const unsigned short* g = (half ? Bt : A)
                + (size_t)((half ? n0 : m0) + c * 16 + (lane >> 2)) * DD + k0 + (lane & 3) * 8;
            unsigned short* l = (half ? Bs : As) + c * 512 + lane * 8;
            gload_lds16(g, l);
        }
        __syncthreads();
        bf16x8 af[4], bfr[4];
#pragma unroll
        for (int mi = 0; mi < 4; mi++)
            af[mi] = *(const bf16x8*)&As[(wm * 64 + mi * 16 + l15) * 32 + quad * 8];
#pragma unroll
        for (int ni = 0; ni < 4; ni++)
            bfr[ni] = *(const bf16x8*)&Bs[(wn * 64 + ni * 16 + l15) * 32 + quad * 8];
#pragma unroll
        for (int mi = 0; mi < 4; mi++)
#pragma unroll
            for (int ni = 0; ni < 4; ni++)
                acc[mi][ni] = __builtin_amdgcn_mfma_f32_16x16x32_bf16(af[mi], bfr[ni], acc[mi][ni], 0, 0, 0);
    }

#pragma unroll
    for (int mi = 0; mi < 4; mi++)
#pragma unroll
        for (int ni = 0; ni < 4; ni++) {
            int n = n0 + wn * 64 + ni * 16 + l15;
            float bv = bias[n];
#pragma unroll
            for (int r = 0; r < 4; r++) {
                int m = m0 + wm * 64 + mi * 16 + quad * 4 + r;
                float v = (acc[mi][ni][r] + bv) * oscale;
                if (mode == 2) {
                    ((float*)out)[(size_t)m * DD + n] = v;
                } else {
                    int bb = m >> 10, s = m & 1023, hh = n >> 6, d = n & 63;
                    size_t head = (size_t)(bb * HH + hh) << 16;
                    size_t off;
                    if (mode == 0) {
                        off = head + (((size_t)(s >> 4) * 2 + (d >> 5)) * 64
                              + ((d >> 3) & 3) * 16 + (s & 15)) * 8 + (d & 7);
                    } else {
                        off = head + (((size_t)(s >> 5) * 4 + (d >> 4)) * 64
                              + ((s >> 3) & 3) * 16 + (d & 15)) * 8 + (s & 7);
                    }
                    ((unsigned short*)out)[off] = f2bf(v);
                }
            }
        }
}

// SCL = (1/8) * log2(e), folded into Q at projection time
#define SCLQ 0.18033688f

__global__ __launch_bounds__(256, 3) void gemm_qkv(
    const unsigned short* __restrict__ xq, const unsigned short* __restrict__ xk,
    const unsigned short* __restrict__ xv,
    const unsigned short* __restrict__ wtq, const unsigned short* __restrict__ wtk,
    const unsigned short* __restrict__ wtv,
    const float* __restrict__ bq, const float* __restrict__ bk, const float* __restrict__ bv,
    unsigned short* __restrict__ q, unsigned short* __restrict__ k, unsigned short* __restrict__ v)
{
    int z = blockIdx.z;
    const unsigned short* A  = z == 0 ? xq  : (z == 1 ? xk  : xv);
    const unsigned short* Bt = z == 0 ? wtq : (z == 1 ? wtk : wtv);
    const float* bias        = z == 0 ? bq  : (z == 1 ? bk  : bv);
    void* out                = z == 0 ? (void*)q : (z == 1 ? (void*)k : (void*)v);
    gemm128_core(A, Bt, bias, out, z == 2 ? 1 : 0, z == 0 ? SCLQ : 1.0f);
}

__global__ __launch_bounds__(256, 3) void gemm_o(
    const unsigned short* __restrict__ x, const unsigned short* __restrict__ wto,
    const float* __restrict__ bo, float* __restrict__ out)
{
    gemm128_core(x, wto, bo, out, 2, 1.0f);
}

// ---------------- fused attention: 1 wave = 1 head, pinned-prefetch pipeline ----------------
// Q pre-scaled by (1/8)*log2e so p = exp2(s). No max-sub (scores ~N(0,1)).
// Pass 1: QK -> row sums, prefetch distance 2 (8 K-frags in flight, asm-pinned).
// Pass 2: recompute p, ds_add wc*p/rs into shared attn_c, LDS C->A transpose
// (same-wave DS order), PV on unnormalized p-hat; prefetch distance 1 for K and V.
// Pass-2 chunk order rotated per wave to de-collide the cross-wave LDS atomics.
#define LDK(f) (*(const bf16x8*)(kh + ((size_t)(f) * 64 + lane) * 8))
#define LDV(f) (*(const bf16x8*)(vh + ((size_t)(f) * 64 + lane) * 8))

__global__ __launch_bounds__(1024, 4) void attn_kernel(
    const unsigned short* __restrict__ qf, const unsigned short* __restrict__ kf,
    const unsigned short* __restrict__ vf, const float* __restrict__ Wc,
    const float* __restrict__ bcp, unsigned short* __restrict__ xout,
    float* __restrict__ attc)
{
    __shared__ float accc[16][1028];               // attn_c accumulator (<=2-way banks)
    __shared__ unsigned short tsc[16][16][36];     // per-wave C->A transpose scratch

    int t = threadIdx.x, w = t >> 6, lane = t & 63, quad = lane >> 4, l15 = lane & 15;
    int b = blockIdx.x >> 6, qt = blockIdx.x & 63;
    int h = w;

    for (int i = t; i < 16 * 1028; i += 1024) (&accc[0][0])[i] = 0.f;
    __syncthreads();                                 // barrier 1 of 2

    const unsigned short* qh = qf + ((size_t)(b * HH + h) << 16);
    const unsigned short* kh = kf + ((size_t)(b * HH + h) << 16);
    const unsigned short* vh = vf + ((size_t)(b * HH + h) << 16);
    float wc = Wc[h], bc = *bcp;
    f32x4 zero = {0.f, 0.f, 0.f, 0.f};

    bf16x8 a0 = *(const bf16x8*)(qh + ((size_t)(qt * 2 + 0) * 64 + lane) * 8);
    bf16x8 a1 = *(const bf16x8*)(qh + ((size_t)(qt * 2 + 1) * 64 + lane) * 8);

    // ---- pass 1: row sums; prefetch distance 2, pinned ----
    float rs[4] = {0.f, 0.f, 0.f, 0.f};
    bf16x8 c0 = LDK(0), c1 = LDK(1), c2 = LDK(2), c3 = LDK(3);
    PIN4(c0, c1, c2, c3);
    bf16x8 d0 = LDK(4), d1 = LDK(5), d2 = LDK(6), d3 = LDK(7);
    PIN4(d0, d1, d2, d3);
#pragma unroll 2
    for (int g = 0; g < 32; g++) {
        int gn = g < 30 ? g + 2 : 31;
        bf16x8 n0 = LDK(gn * 4 + 0), n1 = LDK(gn * 4 + 1);
        bf16x8 n2 = LDK(gn * 4 + 2), n3 = LDK(gn * 4 + 3);
        PIN4(n0, n1, n2, n3);
        f32x4 s0 = zero, s1 = zero;
        s0 = __builtin_amdgcn_mfma_f32_16x16x32_bf16(a0, c0, s0, 0, 0, 0);
        s0 = __builtin_amdgcn_mfma_f32_16x16x32_bf16(a1, c1, s0, 0, 0, 0);
        s1 = __builtin_amdgcn_mfma_f32_16x16x32_bf16(a0, c2, s1, 0, 0, 0);
        s1 = __builtin_amdgcn_mfma_f32_16x16x32_bf16(a1, c3, s1, 0, 0, 0);
#pragma unroll
        for (int r = 0; r < 4; r++) rs[r] += exp2f(s0[r]) + exp2f(s1[r]);
        c0 = d0; c1 = d1; c2 = d2; c3 = d3;
        d0 = n0; d1 = n1; d2 = n2; d3 = n3;
    }
#pragma unroll
    for (int r = 0; r < 4; r++) {
        rs[r] += __shfl_xor(rs[r], 1);
        rs[r] += __shfl_xor(rs[r], 2);
        rs[r] += __shfl_xor(rs[r], 4);
        rs[r] += __shfl_xor(rs[r], 8);
    }
    float invC[4], sC[4];
#pragma unroll
    for (int r = 0; r < 4; r++) { invC[r] = 1.f / rs[r]; sC[r] = wc * invC[r]; }

    // ---- pass 2: attn_c accumulate + PV; prefetch distance 1 (K and V), pinned;
    //      chunk order rotated by 2*w to de-collide cross-wave atomics ----
    f32x4 o0 = zero, o1 = zero, o2 = zero, o3 = zero;
    int cc0 = (2 * w) & 31;
    bf16x8 k0 = LDK(cc0 * 4 + 0), k1 = LDK(cc0 * 4 + 1);
    bf16x8 k2 = LDK(cc0 * 4 + 2), k3 = LDK(cc0 * 4 + 3);
    PIN4(k0, k1, k2, k3);
    bf16x8 v0 = LDV(cc0 * 4 + 0), v1 = LDV(cc0 * 4 + 1);
    bf16x8 v2 = LDV(cc0 * 4 + 2), v3 = LDV(cc0 * 4 + 3);
    PIN4(v0, v1, v2, v3);
#pragma unroll 2
    for (int i = 0; i < 32; i++) {
        int cc = (i + 2 * w) & 31;
        int cn = ((i + 1) + 2 * w) & 31;
        bf16x8 kn0 = LDK(cn * 4 + 0), kn1 = LDK(cn * 4 + 1);
        bf16x8 kn2 = LDK(cn * 4 + 2), kn3 = LDK(cn * 4 + 3);
        PIN4(kn0, kn1, kn2, kn3);
        bf16x8 vn0 = LDV(cn * 4 + 0), vn1 = LDV(cn * 4 + 1);
        bf16x8 vn2 = LDV(cn * 4 + 2), vn3 = LDV(cn * 4 + 3);
        PIN4(vn0, vn1, vn2, vn3);

        f32x4 s0 = zero, s1 = zero;
        s0 = __builtin_amdgcn_mfma_f32_16x16x32_bf16(a0, k0, s0, 0, 0, 0);
        s0 = __builtin_amdgcn_mfma_f32_16x16x32_bf16(a1, k1, s0, 0, 0, 0);
        s1 = __builtin_amdgcn_mfma_f32_16x16x32_bf16(a0, k2, s1, 0, 0, 0);
        s1 = __builtin_amdgcn_mfma_f32_16x16x32_bf16(a1, k3, s1, 0, 0, 0);

#pragma unroll
        for (int r = 0; r < 4; r++) {
            float p0 = exp2f(s0[r]);
            float p1 = exp2f(s1[r]);
            int row = quad * 4 + r;
            tsc[w][row][l15] = f2bf(p0);
            tsc[w][row][16 + l15] = f2bf(p1);
            atomicAdd(&accc[row][cc * 32 + l15], sC[r] * p0);
            atomicAdd(&accc[row][cc * 32 + 16 + l15], sC[r] * p1);
        }
        bf16x8 ap = *(const bf16x8*)&tsc[w][l15][quad * 8];

        o0 = __builtin_amdgcn_mfma_f32_16x16x32_bf16(ap, v0, o0, 0, 0, 0);
        o1 = __builtin_amdgcn_mfma_f32_16x16x32_bf16(ap, v1, o1, 0, 0, 0);
        o2 = __builtin_amdgcn_mfma_f32_16x16x32_bf16(ap, v2, o2, 0, 0, 0);
        o3 = __builtin_amdgcn_mfma_f32_16x16x32_bf16(ap, v3, o3, 0, 0, 0);
        k0 = kn0; k1 = kn1; k2 = kn2; k3 = kn3;
        v0 = vn0; v1 = vn1; v2 = vn2; v3 = vn3;
    }

    // ---- O epilogue (C-layout rows, scaled) ----
    f32x4 oo[4] = {o0, o1, o2, o3};
#pragma unroll
    for (int j = 0; j < 4; j++)
#pragma unroll
        for (int r = 0; r < 4; r++) {
            int row = quad * 4 + r;
            xout[((size_t)(b * SS) + qt * 16 + row) * DD + h * 64 + j * 16 + l15] =
                f2bf(oo[j][r] * invC[r]);
        }

    __syncthreads();                                 // barrier 2 of 2
    for (int i = t; i < 16 * 1024; i += 1024) {
        int row = i >> 10, col = i & 1023;
        attc[((size_t)b * SS + qt * 16 + row) * SS + col] = accc[row][col] + bc;
    }
}

extern "C" void kernel_launch(void* const* d_in, const int* in_sizes, int n_in,
                              void* d_out, int out_size, void* d_ws, size_t ws_size,
                              hipStream_t stream) {
    const float* query = (const float*)d_in[0];
    const float* key   = (const float*)d_in[1];
    const float* value = (const float*)d_in[2];
    const float* Wq = (const float*)d_in[3];
    const float* bq = (const float*)d_in[4];
    const float* Wk = (const float*)d_in[5];
    const float* bk = (const float*)d_in[6];
    const float* Wv = (const float*)d_in[7];
    const float* bv = (const float*)d_in[8];
    const float* Wo = (const float*)d_in[9];
    const float* bo = (const float*)d_in[10];
    const float* Wc = (const float*)d_in[11];
    const float* bc = (const float*)d_in[12];

    unsigned short* ws  = (unsigned short*)d_ws;
    unsigned short* xq  = ws;
    unsigned short* xk  = xq  + (size_t)4194304;
    unsigned short* xv  = xk  + (size_t)4194304;
    unsigned short* wtq = xv  + (size_t)4194304;
    unsigned short* wtk = wtq + (size_t)1048576;
    unsigned short* wtv = wtk + (size_t)1048576;
    unsigned short* wto = wtv + (size_t)1048576;
    unsigned short* qfb = wto + (size_t)1048576;    // Q frag-blocked (pre-scaled)
    unsigned short* kfb = qfb + (size_t)4194304;    // K frag-blocked
    unsigned short* vfb = kfb + (size_t)4194304;    // V frag-blocked
    unsigned short* xat = vfb + (size_t)4194304;    // [b,s,d]

    float* out0 = (float*)d_out;
    float* attc = out0 + (size_t)4194304;

    hipLaunchKernelGGL(cvt3, dim3(4096), dim3(256), 0, stream,
                       query, key, value, xq, xk, xv);
    hipLaunchKernelGGL(wtrans, dim3(32, 32, 4), dim3(256), 0, stream,
                       Wq, Wk, Wv, Wo, wtq, wtk, wtv, wto);
    hipLaunchKernelGGL(gemm_qkv, dim3(8, 32, 3), dim3(256), 0, stream,
                       xq, xk, xv, wtq, wtk, wtv, bq, bk, bv, qfb, kfb, vfb);
    hipLaunchKernelGGL(attn_kernel, dim3(256), dim3(1024), 0, stream,
                       qfb, kfb, vfb, Wc, bc, xat, attc);
    hipLaunchKernelGGL(gemm_o, dim3(8, 32), dim3(256), 0, stream,
                       xat, wto, bo, out0);
}

// Round 6
// 304.602 us; speedup vs baseline: 1.8197x; 1.8197x over previous
//
#include <hip/hip_runtime.h>
#include <hip/hip_bf16.h>

// Problem constants: B=4, S=1024, D=1024, H=16, HD=64
#define SS 1024
#define DD 1024
#define HH 16
#define HDh 64

typedef short bf16x8 __attribute__((ext_vector_type(8)));
typedef float f32x4 __attribute__((ext_vector_type(4)));

__device__ inline unsigned short f2bf(float f) {
    union { __hip_bfloat16 h; unsigned short u; } cv;
    cv.h = __float2bfloat16(f);   // RTNE
    return cv.u;
}
__device__ inline float bf2f(short u) {
    unsigned int x = ((unsigned int)(unsigned short)u) << 16;
    return __uint_as_float(x);
}

#define PIN4(a, b, c, d) asm volatile("" : "+v"(a), "+v"(b), "+v"(c), "+v"(d))

// async global->LDS, 16B per lane; LDS dest = wave-uniform base + lane*16
__device__ inline void gload_lds16(const unsigned short* g, unsigned short* l) {
    __builtin_amdgcn_global_load_lds(
        (const __attribute__((address_space(1))) unsigned int*)g,
        (__attribute__((address_space(3))) unsigned int*)l, 16, 0, 0);
}

// ---------------- fp32 -> bf16 convert for query/key/value ----------------
__global__ __launch_bounds__(256) void cvt3(
    const float* __restrict__ a, const float* __restrict__ b, const float* __restrict__ c,
    unsigned short* __restrict__ oa, unsigned short* __restrict__ ob, unsigned short* __restrict__ oc)
{
    size_t i = ((size_t)blockIdx.x * 256 + threadIdx.x) * 4;
    float4 va = *(const float4*)(a + i);
    float4 vb = *(const float4*)(b + i);
    float4 vc = *(const float4*)(c + i);
    *(ushort4*)(oa + i) = make_ushort4(f2bf(va.x), f2bf(va.y), f2bf(va.z), f2bf(va.w));
    *(ushort4*)(ob + i) = make_ushort4(f2bf(vb.x), f2bf(vb.y), f2bf(vb.z), f2bf(vb.w));
    *(ushort4*)(oc + i) = make_ushort4(f2bf(vc.x), f2bf(vc.y), f2bf(vc.z), f2bf(vc.w));
}

// ------------- weight transpose-convert: Wt[e][d] = bf16(W[d][e]) -------------
__global__ __launch_bounds__(256) void wtrans(
    const float* __restrict__ Wq, const float* __restrict__ Wk,
    const float* __restrict__ Wv, const float* __restrict__ Wo,
    unsigned short* __restrict__ oq, unsigned short* __restrict__ ok,
    unsigned short* __restrict__ ov, unsigned short* __restrict__ oo)
{
    __shared__ float tile[32][33];
    int z = blockIdx.z;
    const float* W = z == 0 ? Wq : (z == 1 ? Wk : (z == 2 ? Wv : Wo));
    unsigned short* O = z == 0 ? oq : (z == 1 ? ok : (z == 2 ? ov : oo));
    int e0 = blockIdx.x * 32, d0 = blockIdx.y * 32;
    int r = threadIdx.x >> 3, c4 = (threadIdx.x & 7) * 4;
    float4 v = *(const float4*)(W + (size_t)(d0 + r) * DD + e0 + c4);
    tile[r][c4 + 0] = v.x; tile[r][c4 + 1] = v.y; tile[r][c4 + 2] = v.z; tile[r][c4 + 3] = v.w;
    __syncthreads();
    ushort4 u = make_ushort4(f2bf(tile[c4 + 0][r]), f2bf(tile[c4 + 1][r]),
                             f2bf(tile[c4 + 2][r]), f2bf(tile[c4 + 3][r]));
    *(ushort4*)(O + (size_t)(e0 + r) * DD + d0 + c4) = u;
}

// ---------------- 128x128 bf16 MFMA GEMM core, m97-style staging ----------------
__device__ inline void gemm128_core(const unsigned short* __restrict__ A,
                                    const unsigned short* __restrict__ Bt,
                                    const float* __restrict__ bias,
                                    void* __restrict__ out, int mode, float oscale)
{
    __shared__ unsigned short As[128 * 32];   // 8 KB
    __shared__ unsigned short Bs[128 * 32];   // 8 KB
    int t = threadIdx.x;
    int m0 = blockIdx.y * 128, n0 = blockIdx.x * 128;
    int w = t >> 6, lane = t & 63, quad = lane >> 4, l15 = lane & 15;
    int wm = w >> 1, wn = w & 1;

    f32x4 zero = {0.f, 0.f, 0.f, 0.f};
    f32x4 acc[4][4];
#pragma unroll
    for (int i = 0; i < 4; i++)
#pragma unroll
        for (int j = 0; j < 4; j++) acc[i][j] = zero;

    for (int k0 = 0; k0 < DD; k0 += 32) {
        __syncthreads();
#pragma unroll
        for (int i = 0; i < 4; i++) {
            int chunk = w + i * 4;            // 0..15
            int half = chunk >> 3;            // 0=A, 1=B
            int c = chunk & 7;                // 16-row chunk within matrix
            const unsigned short* g = (half ? Bt : A)
                + (size_t)((half ? n0 : m0) + c * 16 + (lane >> 2)) * DD + k0 + (lane & 3) * 8;
            unsigned short* l = (half ? Bs : As) + c * 512 + lane * 8;
            gload_lds16(g, l);
        }
        __syncthreads();
        bf16x8 af[4], bfr[4];
#pragma unroll
        for (int mi = 0; mi < 4; mi++)
            af[mi] = *(const bf16x8*)&As[(wm * 64 + mi * 16 + l15) * 32 + quad * 8];
#pragma unroll
        for (int ni = 0; ni < 4; ni++)
            bfr[ni] = *(const bf16x8*)&Bs[(wn * 64 + ni * 16 + l15) * 32 + quad * 8];
#pragma unroll
        for (int mi = 0; mi < 4; mi++)
#pragma unroll
            for (int ni = 0; ni < 4; ni++)
                acc[mi][ni] = __builtin_amdgcn_mfma_f32_16x16x32_bf16(af[mi], bfr[ni], acc[mi][ni], 0, 0, 0);
    }

#pragma unroll
    for (int mi = 0; mi < 4; mi++)
#pragma unroll
        for (int ni = 0; ni < 4; ni++) {
            int n = n0 + wn * 64 + ni * 16 + l15;
            float bv = bias[n];
#pragma unroll
            for (int r = 0; r < 4; r++) {
                int m = m0 + wm * 64 + mi * 16 + quad * 4 + r;
                float v = (acc[mi][ni][r] + bv) * oscale;
                if (mode == 2) {
                    ((float*)out)[(size_t)m * DD + n] = v;
                } else {
                    int bb = m >> 10, s = m & 1023, hh = n >> 6, d = n & 63;
                    size_t head = (size_t)(bb * HH + hh) << 16;
                    size_t off;
                    if (mode == 0) {
                        off = head + (((size_t)(s >> 4) * 2 + (d >> 5)) * 64
                              + ((d >> 3) & 3) * 16 + (s & 15)) * 8 + (d & 7);
                    } else {
                        off = head + (((size_t)(s >> 5) * 4 + (d >> 4)) * 64
                              + ((s >> 3) & 3) * 16 + (d & 15)) * 8 + (s & 7);
                    }
                    ((unsigned short*)out)[off] = f2bf(v);
                }
            }
        }
}

// SCL = (1/8) * log2(e), folded into Q at projection time
#define SCLQ 0.18033688f

__global__ __launch_bounds__(256, 3) void gemm_qkv(
    const unsigned short* __restrict__ xq, const unsigned short* __restrict__ xk,
    const unsigned short* __restrict__ xv,
    const unsigned short* __restrict__ wtq, const unsigned short* __restrict__ wtk,
    const unsigned short* __restrict__ wtv,
    const float* __restrict__ bq, const float* __restrict__ bk, const float* __restrict__ bv,
    unsigned short* __restrict__ q, unsigned short* __restrict__ k, unsigned short* __restrict__ v)
{
    int z = blockIdx.z;
    const unsigned short* A  = z == 0 ? xq  : (z == 1 ? xk  : xv);
    const unsigned short* Bt = z == 0 ? wtq : (z == 1 ? wtk : wtv);
    const float* bias        = z == 0 ? bq  : (z == 1 ? bk  : bv);
    void* out                = z == 0 ? (void*)q : (z == 1 ? (void*)k : (void*)v);
    gemm128_core(A, Bt, bias, out, z == 2 ? 1 : 0, z == 0 ? SCLQ : 1.0f);
}

__global__ __launch_bounds__(256, 3) void gemm_o(
    const unsigned short* __restrict__ x, const unsigned short* __restrict__ wto,
    const float* __restrict__ bo, float* __restrict__ out)
{
    gemm128_core(x, wto, bo, out, 2, 1.0f);
}

// =========================================================================
// FAST PATH: materialized-P attention (3 GEMM-shaped streaming kernels)
// P-hat layout per (b,h): [kc=k/32][mt=q/16][lane][8] where
//   lane = (k16half)*16 + (q&15), j = k&7  (A-frag blocked for PV staging)
// =========================================================================

// ---- K1: S=QK^T (pre-scaled), exp2, row-sums -> Z (atomic), P-hat store ----
__global__ __launch_bounds__(256, 3) void qk_exp_kernel(
    const unsigned short* __restrict__ qf, const unsigned short* __restrict__ kf,
    float* __restrict__ Z, unsigned short* __restrict__ phat)
{
    __shared__ unsigned short sm[128 * 132];   // stage: first 16384; transpose: all
    int t = threadIdx.x, w = t >> 6, lane = t & 63, quad = lane >> 4, l15 = lane & 15;
    int n0 = blockIdx.x * 128, m0 = blockIdx.y * 128, bh = blockIdx.z;
    int wm = w >> 1, wn = w & 1;
    const unsigned short* qh = qf + ((size_t)bh << 16);
    const unsigned short* kh = kf + ((size_t)bh << 16);

    // stage 16 A-frags + 16 B-frags (frag-blocked source -> lane-linear LDS)
#pragma unroll
    for (int i = 0; i < 8; i++) {
        int c = w + i * 4;
        const unsigned short* g = (c < 16)
            ? qh + (size_t)((m0 >> 3) + c) * 512 + lane * 8
            : kh + (size_t)((n0 >> 3) + (c - 16)) * 512 + lane * 8;
        gload_lds16(g, sm + c * 512 + lane * 8);
    }
    __syncthreads();

    f32x4 zero = {0.f, 0.f, 0.f, 0.f};
    f32x4 acc[4][4];
#pragma unroll
    for (int i = 0; i < 4; i++)
#pragma unroll
        for (int j = 0; j < 4; j++) acc[i][j] = zero;
#pragma unroll
    for (int kh_ = 0; kh_ < 2; kh_++) {
        bf16x8 af[4], bfr[4];
#pragma unroll
        for (int mi = 0; mi < 4; mi++)
            af[mi] = *(const bf16x8*)&sm[((wm * 4 + mi) * 2 + kh_) * 512 + lane * 8];
#pragma unroll
        for (int ni = 0; ni < 4; ni++)
            bfr[ni] = *(const bf16x8*)&sm[8192 + ((wn * 4 + ni) * 2 + kh_) * 512 + lane * 8];
#pragma unroll
        for (int mi = 0; mi < 4; mi++)
#pragma unroll
            for (int ni = 0; ni < 4; ni++)
                acc[mi][ni] = __builtin_amdgcn_mfma_f32_16x16x32_bf16(af[mi], bfr[ni], acc[mi][ni], 0, 0, 0);
    }

    // exp in place + row sums -> global atomic Z
#pragma unroll
    for (int mi = 0; mi < 4; mi++) {
#pragma unroll
        for (int ni = 0; ni < 4; ni++)
#pragma unroll
            for (int r = 0; r < 4; r++)
                acc[mi][ni][r] = exp2f(acc[mi][ni][r]);
#pragma unroll
        for (int r = 0; r < 4; r++) {
            float s = acc[mi][0][r] + acc[mi][1][r] + acc[mi][2][r] + acc[mi][3][r];
            s += __shfl_xor(s, 1);
            s += __shfl_xor(s, 2);
            s += __shfl_xor(s, 4);
            s += __shfl_xor(s, 8);
            if (l15 == 0)
                atomicAdd(&Z[(size_t)bh * 1024 + m0 + wm * 64 + mi * 16 + quad * 4 + r], s);
        }
    }
    __syncthreads();   // all staged-LDS reads complete before reuse

    // C-layout -> LDS tile [128][132]
#pragma unroll
    for (int mi = 0; mi < 4; mi++)
#pragma unroll
        for (int ni = 0; ni < 4; ni++)
#pragma unroll
            for (int r = 0; r < 4; r++)
                sm[(wm * 64 + mi * 16 + quad * 4 + r) * 132 + wn * 64 + ni * 16 + l15] =
                    f2bf(acc[mi][ni][r]);
    __syncthreads();

    // frag-order coalesced global store of the 128x128 tile
#pragma unroll
    for (int u = 0; u < 8; u++) {
        int wi = t + u * 256;                  // 0..2047
        int kc = wi >> 9, mt = (wi >> 6) & 7, ln = wi & 63;
        bf16x8 v = *(const bf16x8*)&sm[(mt * 16 + (ln & 15)) * 132 + kc * 32 + (ln >> 4) * 8];
        *(bf16x8*)(phat + (((size_t)bh * 32 + (n0 >> 5) + kc) * 64 + (m0 >> 4) + mt) * 512 + ln * 8) = v;
    }
}

// ---- K2: attn_c = bc + sum_h wc[h]/Z[h,q] * P-hat ----
__global__ __launch_bounds__(256) void attn_c_kernel(
    const unsigned short* __restrict__ phat, const float* __restrict__ Z,
    const float* __restrict__ Wc, const float* __restrict__ bcp,
    float* __restrict__ attc)
{
    int t = blockIdx.x * 256 + threadIdx.x;    // 0..524287
    int lane = t & 63, mt = (t >> 6) & 63, kc = (t >> 12) & 31, b = t >> 17;
    int l15 = lane & 15;
    int q = mt * 16 + l15;
    float acc[8] = {0.f, 0.f, 0.f, 0.f, 0.f, 0.f, 0.f, 0.f};
#pragma unroll 4
    for (int h = 0; h < 16; h++) {
        int bh = b * 16 + h;
        float wz = Wc[h] / Z[(size_t)bh * 1024 + q];
        bf16x8 p = *(const bf16x8*)(phat + (((size_t)bh * 32 + kc) * 64 + mt) * 512 + lane * 8);
#pragma unroll
        for (int j = 0; j < 8; j++) acc[j] += wz * bf2f(p[j]);
    }
    float bc = *bcp;
    float* dst = attc + ((size_t)b * 1024 + q) * 1024 + kc * 32 + (lane >> 4) * 8;
    float4 A0 = {acc[0] + bc, acc[1] + bc, acc[2] + bc, acc[3] + bc};
    float4 A1 = {acc[4] + bc, acc[5] + bc, acc[6] + bc, acc[7] + bc};
    *(float4*)dst = A0;
    *(float4*)(dst + 4) = A1;
}

// ---- K3: O = (P-hat . V) / Z, staged 2-barrier K-loop (m97 shape) ----
__global__ __launch_bounds__(256, 4) void pv_kernel(
    const unsigned short* __restrict__ phat, const unsigned short* __restrict__ vf,
    const float* __restrict__ Z, unsigned short* __restrict__ xat)
{
    __shared__ unsigned short sm[6144];        // A: 8 frags (4096), B: 4 frags (2048)
    int t = threadIdx.x, w = t >> 6, lane = t & 63, quad = lane >> 4, l15 = lane & 15;
    int m0 = blockIdx.x * 128, bh = blockIdx.y;
    int b = bh >> 4, h = bh & 15;
    const unsigned short* vh = vf + ((size_t)bh << 16);

    f32x4 zero = {0.f, 0.f, 0.f, 0.f};
    f32x4 acc[2][4];
#pragma unroll
    for (int i = 0; i < 2; i++)
#pragma unroll
        for (int j = 0; j < 4; j++) acc[i][j] = zero;

    for (int kc = 0; kc < 32; kc++) {
        __syncthreads();
#pragma unroll
        for (int i = 0; i < 3; i++) {
            int c = w + i * 4;                 // 0..11
            const unsigned short* g = (c < 8)
                ? phat + (((size_t)bh * 32 + kc) * 64 + (m0 >> 4) + c) * 512 + lane * 8
                : vh + ((size_t)(kc * 4 + (c - 8)) * 64 + lane) * 8;
            gload_lds16(g, sm + c * 512 + lane * 8);
        }
        __syncthreads();
        bf16x8 a2[2], b4[4];
#pragma unroll
        for (int i2 = 0; i2 < 2; i2++)
            a2[i2] = *(const bf16x8*)&sm[(w * 2 + i2) * 512 + lane * 8];
#pragma unroll
        for (int ni = 0; ni < 4; ni++)
            b4[ni] = *(const bf16x8*)&sm[4096 + ni * 512 + lane * 8];
#pragma unroll
        for (int i2 = 0; i2 < 2; i2++)
#pragma unroll
            for (int ni = 0; ni < 4; ni++)
                acc[i2][ni] = __builtin_amdgcn_mfma_f32_16x16x32_bf16(a2[i2], b4[ni], acc[i2][ni], 0, 0, 0);
    }

#pragma unroll
    for (int i2 = 0; i2 < 2; i2++)
#pragma unroll
        for (int r = 0; r < 4; r++) {
            int q = m0 + w * 32 + i2 * 16 + quad * 4 + r;
            float iz = 1.f / Z[(size_t)bh * 1024 + q];
#pragma unroll
            for (int ni = 0; ni < 4; ni++)
                xat[((size_t)(b * 1024 + q)) * 1024 + h * 64 + ni * 16 + l15] =
                    f2bf(acc[i2][ni][r] * iz);
        }
}

// =========================================================================
// FALLBACK: R5 fused attention (used when ws_size < fast-path requirement)
// =========================================================================
#define LDK(f) (*(const bf16x8*)(kh + ((size_t)(f) * 64 + lane) * 8))
#define LDV(f) (*(const bf16x8*)(vh + ((size_t)(f) * 64 + lane) * 8))

__global__ __launch_bounds__(1024, 4) void attn_kernel(
    const unsigned short* __restrict__ qf, const unsigned short* __restrict__ kf,
    const unsigned short* __restrict__ vf, const float* __restrict__ Wc,
    const float* __restrict__ bcp, unsigned short* __restrict__ xout,
    float* __restrict__ attc)
{
    __shared__ float accc[16][1028];
    __shared__ unsigned short tsc[16][16][36];

    int t = threadIdx.x, w = t >> 6, lane = t & 63, quad = lane >> 4, l15 = lane & 15;
    int b = blockIdx.x >> 6, qt = blockIdx.x & 63;
    int h = w;

    for (int i = t; i < 16 * 1028; i += 1024) (&accc[0][0])[i] = 0.f;
    __syncthreads();

    const unsigned short* qh = qf + ((size_t)(b * HH + h) << 16);
    const unsigned short* kh = kf + ((size_t)(b * HH + h) << 16);
    const unsigned short* vh = vf + ((size_t)(b * HH + h) << 16);
    float wc = Wc[h], bc = *bcp;
    f32x4 zero = {0.f, 0.f, 0.f, 0.f};

    bf16x8 a0 = *(const bf16x8*)(qh + ((size_t)(qt * 2 + 0) * 64 + lane) * 8);
    bf16x8 a1 = *(const bf16x8*)(qh + ((size_t)(qt * 2 + 1) * 64 + lane) * 8);

    float rs[4] = {0.f, 0.f, 0.f, 0.f};
    bf16x8 c0 = LDK(0), c1 = LDK(1), c2 = LDK(2), c3 = LDK(3);
    PIN4(c0, c1, c2, c3);
    bf16x8 d0 = LDK(4), d1 = LDK(5), d2 = LDK(6), d3 = LDK(7);
    PIN4(d0, d1, d2, d3);
#pragma unroll 2
    for (int g = 0; g < 32; g++) {
        int gn = g < 30 ? g + 2 : 31;
        bf16x8 n0 = LDK(gn * 4 + 0), n1 = LDK(gn * 4 + 1);
        bf16x8 n2 = LDK(gn * 4 + 2), n3 = LDK(gn * 4 + 3);
        PIN4(n0, n1, n2, n3);
        f32x4 s0 = zero, s1 = zero;
        s0 = __builtin_amdgcn_mfma_f32_16x16x32_bf16(a0, c0, s0, 0, 0, 0);
        s0 = __builtin_amdgcn_mfma_f32_16x16x32_bf16(a1, c1, s0, 0, 0, 0);
        s1 = __builtin_amdgcn_mfma_f32_16x16x32_bf16(a0, c2, s1, 0, 0, 0);
        s1 = __builtin_amdgcn_mfma_f32_16x16x32_bf16(a1, c3, s1, 0, 0, 0);
#pragma unroll
        for (int r = 0; r < 4; r++) rs[r] += exp2f(s0[r]) + exp2f(s1[r]);
        c0 = d0; c1 = d1; c2 = d2; c3 = d3;
        d0 = n0; d1 = n1; d2 = n2; d3 = n3;
    }
#pragma unroll
    for (int r = 0; r < 4; r++) {
        rs[r] += __shfl_xor(rs[r], 1);
        rs[r] += __shfl_xor(rs[r], 2);
        rs[r] += __shfl_xor(rs[r], 4);
        rs[r] += __shfl_xor(rs[r], 8);
    }
    float invC[4], sC[4];
#pragma unroll
    for (int r = 0; r < 4; r++) { invC[r] = 1.f / rs[r]; sC[r] = wc * invC[r]; }

    f32x4 o0 = zero, o1 = zero, o2 = zero, o3 = zero;
    int cc0 = (2 * w) & 31;
    bf16x8 k0 = LDK(cc0 * 4 + 0), k1 = LDK(cc0 * 4 + 1);
    bf16x8 k2 = LDK(cc0 * 4 + 2), k3 = LDK(cc0 * 4 + 3);
    PIN4(k0, k1, k2, k3);
    bf16x8 v0 = LDV(cc0 * 4 + 0), v1 = LDV(cc0 * 4 + 1);
    bf16x8 v2 = LDV(cc0 * 4 + 2), v3 = LDV(cc0 * 4 + 3);
    PIN4(v0, v1, v2, v3);
#pragma unroll 2
    for (int i = 0; i < 32; i++) {
        int cc = (i + 2 * w) & 31;
        int cn = ((i + 1) + 2 * w) & 31;
        bf16x8 kn0 = LDK(cn * 4 + 0), kn1 = LDK(cn * 4 + 1);
        bf16x8 kn2 = LDK(cn * 4 + 2), kn3 = LDK(cn * 4 + 3);
        PIN4(kn0, kn1, kn2, kn3);
        bf16x8 vn0 = LDV(cn * 4 + 0), vn1 = LDV(cn * 4 + 1);
        bf16x8 vn2 = LDV(cn * 4 + 2), vn3 = LDV(cn * 4 + 3);
        PIN4(vn0, vn1, vn2, vn3);

        f32x4 s0 = zero, s1 = zero;
        s0 = __builtin_amdgcn_mfma_f32_16x16x32_bf16(a0, k0, s0, 0, 0, 0);
        s0 = __builtin_amdgcn_mfma_f32_16x16x32_bf16(a1, k1, s0, 0, 0, 0);
        s1 = __builtin_amdgcn_mfma_f32_16x16x32_bf16(a0, k2, s1, 0, 0, 0);
        s1 = __builtin_amdgcn_mfma_f32_16x16x32_bf16(a1, k3, s1, 0, 0, 0);

#pragma unroll
        for (int r = 0; r < 4; r++) {
            float p0 = exp2f(s0[r]);
            float p1 = exp2f(s1[r]);
            int row = quad * 4 + r;
            tsc[w][row][l15] = f2bf(p0);
            tsc[w][row][16 + l15] = f2bf(p1);
            atomicAdd(&accc[row][cc * 32 + l15], sC[r] * p0);
            atomicAdd(&accc[row][cc * 32 + 16 + l15], sC[r] * p1);
        }
        bf16x8 ap = *(const bf16x8*)&tsc[w][l15][quad * 8];

        o0 = __builtin_amdgcn_mfma_f32_16x16x32_bf16(ap, v0, o0, 0, 0, 0);
        o1 = __builtin_amdgcn_mfma_f32_16x16x32_bf16(ap, v1, o1, 0, 0, 0);
        o2 = __builtin_amdgcn_mfma_f32_16x16x32_bf16(ap, v2, o2, 0, 0, 0);
        o3 = __builtin_amdgcn_mfma_f32_16x16x32_bf16(ap, v3, o3, 0, 0, 0);
        k0 = kn0; k1 = kn1; k2 = kn2; k3 = kn3;
        v0 = vn0; v1 = vn1; v2 = vn2; v3 = vn3;
    }

    f32x4 oo[4] = {o0, o1, o2, o3};
#pragma unroll
    for (int j = 0; j < 4; j++)
#pragma unroll
        for (int r = 0; r < 4; r++) {
            int row = quad * 4 + r;
            xout[((size_t)(b * SS) + qt * 16 + row) * DD + h * 64 + j * 16 + l15] =
                f2bf(oo[j][r] * invC[r]);
        }

    __syncthreads();
    for (int i = t; i < 16 * 1024; i += 1024) {
        int row = i >> 10, col = i & 1023;
        attc[((size_t)b * SS + qt * 16 + row) * SS + col] = accc[row][col] + bc;
    }
}

extern "C" void kernel_launch(void* const* d_in, const int* in_sizes, int n_in,
                              void* d_out, int out_size, void* d_ws, size_t ws_size,
                              hipStream_t stream) {
    const float* query = (const float*)d_in[0];
    const float* key   = (const float*)d_in[1];
    const float* value = (const float*)d_in[2];
    const float* Wq = (const float*)d_in[3];
    const float* bq = (const float*)d_in[4];
    const float* Wk = (const float*)d_in[5];
    const float* bk = (const float*)d_in[6];
    const float* Wv = (const float*)d_in[7];
    const float* bv = (const float*)d_in[8];
    const float* Wo = (const float*)d_in[9];
    const float* bo = (const float*)d_in[10];
    const float* Wc = (const float*)d_in[11];
    const float* bc = (const float*)d_in[12];

    unsigned short* ws  = (unsigned short*)d_ws;
    unsigned short* xq  = ws;
    unsigned short* xk  = xq  + (size_t)4194304;
    unsigned short* xv  = xk  + (size_t)4194304;
    unsigned short* wtq = xv  + (size_t)4194304;
    unsigned short* wtk = wtq + (size_t)1048576;
    unsigned short* wtv = wtk + (size_t)1048576;
    unsigned short* wto = wtv + (size_t)1048576;
    unsigned short* qfb = wto + (size_t)1048576;    // Q frag-blocked (pre-scaled)
    unsigned short* kfb = qfb + (size_t)4194304;    // K frag-blocked
    unsigned short* vfb = kfb + (size_t)4194304;    // V frag-blocked
    unsigned short* xat = vfb + (size_t)4194304;    // [b,s,d]

    float* out0 = (float*)d_out;
    float* attc = out0 + (size_t)4194304;

    // fast-path extra workspace: Z (256KB) + P-hat (128MB)
    const size_t base_bytes = 67108864;             // 32M ushorts above
    const size_t z_bytes = 262144;
    const size_t phat_bytes = 134217728;
    bool fast = ws_size >= base_bytes + z_bytes + phat_bytes;

    hipLaunchKernelGGL(cvt3, dim3(4096), dim3(256), 0, stream,
                       query, key, value, xq, xk, xv);
    hipLaunchKernelGGL(wtrans, dim3(32, 32, 4), dim3(256), 0, stream,
                       Wq, Wk, Wv, Wo, wtq, wtk, wtv, wto);
    hipLaunchKernelGGL(gemm_qkv, dim3(8, 32, 3), dim3(256), 0, stream,
                       xq, xk, xv, wtq, wtk, wtv, bq, bk, bv, qfb, kfb, vfb);

    if (fast) {
        float* Zbuf = (float*)((char*)d_ws + base_bytes);
        unsigned short* phat = (unsigned short*)((char*)d_ws + base_bytes + z_bytes);
        hipMemsetAsync(Zbuf, 0, z_bytes, stream);
        hipLaunchKernelGGL(qk_exp_kernel, dim3(8, 8, 64), dim3(256), 0, stream,
                           qfb, kfb, Zbuf, phat);
        hipLaunchKernelGGL(attn_c_kernel, dim3(2048), dim3(256), 0, stream,
                           phat, Zbuf, Wc, bc, attc);
        hipLaunchKernelGGL(pv_kernel, dim3(8, 64), dim3(256), 0, stream,
                           phat, vfb, Zbuf, xat);
    } else {
        hipLaunchKernelGGL(attn_kernel, dim3(256), dim3(1024), 0, stream,
                           qfb, kfb, vfb, Wc, bc, xat, attc);
    }

    hipLaunchKernelGGL(gemm_o, dim3(8, 32), dim3(256), 0, stream,
                       xat, wto, bo, out0);
}